// Round 3
// baseline (503.098 us; speedup 1.0000x reference)
//
#include <hip/hip_runtime.h>
#include <stdint.h>

#define S_LEN 4096
#define D_DIM 2048
#define NHEAD 16
#define HDIM  128

typedef short bf16x8 __attribute__((ext_vector_type(8)));
typedef float f32x4  __attribute__((ext_vector_type(4)));
typedef float f32x16 __attribute__((ext_vector_type(16)));

__device__ __forceinline__ unsigned short f2bf(float x) {
  union { float f; unsigned u; } v; v.f = x;
  unsigned r = v.u + 0x7FFFu + ((v.u >> 16) & 1u);  // RNE
  return (unsigned short)(r >> 16);
}

__device__ __forceinline__ unsigned cvtpk_bf16(float lo, float hi_) {
  unsigned r;
  asm("v_cvt_pk_bf16_f32 %0, %1, %2" : "=v"(r) : "v"(lo), "v"(hi_));
  return r;
}

__device__ __forceinline__ void gload_lds16(const void* g, void* l) {
  __builtin_amdgcn_global_load_lds(
      (const __attribute__((address_space(1))) unsigned int*)g,
      (__attribute__((address_space(3))) unsigned int*)l, 16, 0, 0);
}

// ---------------- fp32 -> bf16 convert (vectorized, memory-bound) ----------
__global__ __launch_bounds__(256) void cvt_bf16(const float* __restrict__ in,
                                                unsigned short* __restrict__ out,
                                                int n) {
  int i = (blockIdx.x * 256 + threadIdx.x) * 8;
  if (i >= n) return;
  float4 a = *(const float4*)(in + i);
  float4 b = *(const float4*)(in + i + 4);
  union { unsigned short s[8]; bf16x8 v; } o;
  o.s[0] = f2bf(a.x); o.s[1] = f2bf(a.y); o.s[2] = f2bf(a.z); o.s[3] = f2bf(a.w);
  o.s[4] = f2bf(b.x); o.s[5] = f2bf(b.y); o.s[6] = f2bf(b.z); o.s[7] = f2bf(b.w);
  *(bf16x8*)(out + i) = o.v;
}

// ---------------- bf16 GEMM, C[m,n] = sum_k A[m,k]*B[n,k] + bias[n] --------
template<bool OUT_BF16>
__global__ __launch_bounds__(256, 2) void gemm_bt(
    const unsigned short* __restrict__ A, const unsigned short* __restrict__ B,
    const float* __restrict__ bias, void* __restrict__ Cout,
    int M, int N, int K) {
  __shared__ __attribute__((aligned(16))) unsigned short As[128 * 32];
  __shared__ __attribute__((aligned(16))) unsigned short Bs[128 * 32];
  const int m0 = blockIdx.y * 128, n0 = blockIdx.x * 128;
  const int tid = threadIdx.x, lane = tid & 63, wv = tid >> 6;
  const int wm = wv >> 1, wn = wv & 1;
  const int rA = lane & 15, kb = (lane >> 4) * 8;

  f32x4 acc[4][4];
#pragma unroll
  for (int i = 0; i < 4; ++i)
#pragma unroll
    for (int j = 0; j < 4; ++j)
#pragma unroll
      for (int r = 0; r < 4; ++r) acc[i][j][r] = 0.f;

  for (int k0 = 0; k0 < K; k0 += 32) {
    __syncthreads();
#pragma unroll
    for (int p = 0; p < 2; ++p) {
      const int rr = (wv * 2 + p) * 16 + (lane >> 2);
      const int cc = lane & 3;
      gload_lds16(A + (size_t)(m0 + rr) * K + k0 + cc * 8, As + (wv * 2 + p) * 512);
      gload_lds16(B + (size_t)(n0 + rr) * K + k0 + cc * 8, Bs + (wv * 2 + p) * 512);
    }
    __syncthreads();
    bf16x8 af[4], bfr[4];
#pragma unroll
    for (int i = 0; i < 4; ++i)
      af[i] = *(const bf16x8*)(As + (wm * 64 + i * 16 + rA) * 32 + kb);
#pragma unroll
    for (int j = 0; j < 4; ++j)
      bfr[j] = *(const bf16x8*)(Bs + (wn * 64 + j * 16 + rA) * 32 + kb);
#pragma unroll
    for (int i = 0; i < 4; ++i)
#pragma unroll
      for (int j = 0; j < 4; ++j)
        acc[i][j] = __builtin_amdgcn_mfma_f32_16x16x32_bf16(af[i], bfr[j], acc[i][j], 0, 0, 0);
  }

  const int cR = (lane >> 4) * 4, cC = lane & 15;
#pragma unroll
  for (int j = 0; j < 4; ++j) {
    const int col = n0 + wn * 64 + j * 16 + cC;
    const float bv = bias[col];
#pragma unroll
    for (int i = 0; i < 4; ++i) {
      const int row0 = m0 + wm * 64 + i * 16 + cR;
#pragma unroll
      for (int r = 0; r < 4; ++r) {
        const float v = acc[i][j][r] + bv;
        if (OUT_BF16)
          ((unsigned short*)Cout)[(size_t)(row0 + r) * N + col] = f2bf(v);
        else
          ((float*)Cout)[(size_t)(row0 + r) * N + col] = v;
      }
    }
  }
}

// ---------------- causal flash attention, round 3 --------------------------
// 4 warps x 32 q-rows; KVBLK=64; swapped QK^T (mfma(K,Q)).
// K: loaded straight global->reg per lane (L1-served: 4 waves share addrs);
//    no K LDS, no K staging, no K barrier dependence.
// V: double-buffered LDS [2][hd=128][key=64], XOR-swizzled, reg-staged with
//    loads issued at top of iteration (T14) and ds_writes after compute;
//    exactly ONE __syncthreads per tile.
// Grid: 1D 512, LPT order (heaviest q-tiles first): qi = 31-(bid>>4).
__global__ __launch_bounds__(256, 2) void attn_fwd3(
    const unsigned short* __restrict__ Qb, const unsigned short* __restrict__ Kb,
    const unsigned short* __restrict__ Vb, unsigned short* __restrict__ Ob) {
  __shared__ __attribute__((aligned(16))) unsigned short Vt[2][128 * 64];
  const int bid = blockIdx.x;
  const int h = bid & 15;
  const int qi = 31 - (bid >> 4);     // LPT: longest jobs dispatch first
  const int q0 = qi * 128;
  const int tid = threadIdx.x, lane = tid & 63, wv = tid >> 6;
  const int qc = lane & 31, hi = lane >> 5;
  const int q0w = q0 + wv * 32;
  const int myq = q0w + qc;

  // V staging thread mapping: key-pair kp, hd-chunk hb
  const int kp = tid & 31, hb = (tid >> 5) * 16;

  // Q as B-operand fragments: qf[sl] = Q[myq][sl*16 + hi*8 .. +8]
  bf16x8 qf[8];
#pragma unroll
  for (int sl = 0; sl < 8; ++sl)
    qf[sl] = *(const bf16x8*)(Qb + (size_t)myq * D_DIM + h * HDIM + sl * 16 + hi * 8);

  f32x16 oacc[4];
#pragma unroll
  for (int nf = 0; nf < 4; ++nf)
#pragma unroll
    for (int r = 0; r < 16; ++r) oacc[nf][r] = 0.f;
  float mh = -3.0e38f, l = 0.f;
  const float c1 = 0.08838834764831845f * 1.44269504089f;  // scale * log2(e)

  const int nt = q0 / 64 + 2;
  const int wqmax = q0w + 31;

  // ---- prologue: stage V tile 0 into buf 0 ----
  {
    const unsigned short* s0 = Vb + (size_t)(2 * kp) * D_DIM + h * HDIM + hb;
    union { uint4 u[2]; unsigned short s[16]; } r0, r1;
    r0.u[0] = *(const uint4*)s0;           r0.u[1] = *(const uint4*)(s0 + 8);
    r1.u[0] = *(const uint4*)(s0 + D_DIM); r1.u[1] = *(const uint4*)(s0 + D_DIM + 8);
#pragma unroll
    for (int w = 0; w < 16; ++w) {
      const int hd = hb + w;
      const unsigned val = (unsigned)r0.s[w] | ((unsigned)r1.s[w] << 16);
      *(unsigned*)((char*)Vt[0] + hd * 128 + (((kp >> 2) ^ (hd & 7)) << 4) + ((kp & 3) << 2)) = val;
    }
  }
  __syncthreads();

  for (int kt = 0; kt < nt; ++kt) {
    const int k0 = kt * 64;
    const int cur = kt & 1, nxt = cur ^ 1;
    // ---- issue V global loads for next tile (hidden under compute) ----
    const int kpre = (kt + 1 < nt) ? k0 + 64 : k0;  // clamp: last iter reloads
    union { uint4 u[2]; unsigned short s[16]; } r0, r1;
    {
      const unsigned short* s0 = Vb + (size_t)(kpre + 2 * kp) * D_DIM + h * HDIM + hb;
      r0.u[0] = *(const uint4*)s0;           r0.u[1] = *(const uint4*)(s0 + 8);
      r1.u[0] = *(const uint4*)(s0 + D_DIM); r1.u[1] = *(const uint4*)(s0 + D_DIM + 8);
    }

    if (k0 <= wqmax) {
      // --- QK^T (swapped): K frags straight from global (L1-resident) ---
      f32x16 sacc[2];
#pragma unroll
      for (int kb = 0; kb < 2; ++kb)
#pragma unroll
        for (int r = 0; r < 16; ++r) sacc[kb][r] = 0.f;
#pragma unroll
      for (int kb = 0; kb < 2; ++kb) {
        const unsigned short* krow = Kb + (size_t)(k0 + kb * 32 + qc) * D_DIM + h * HDIM + hi * 8;
        bf16x8 kfr[8];
#pragma unroll
        for (int sl = 0; sl < 8; ++sl)
          kfr[sl] = *(const bf16x8*)(krow + sl * 16);
#pragma unroll
        for (int sl = 0; sl < 8; ++sl)
          sacc[kb] = __builtin_amdgcn_mfma_f32_32x32x16_bf16(kfr[sl], qf[sl], sacc[kb], 0, 0, 0);
      }

      // --- in-register online softmax (log2 domain) ---
      const bool needmask = (k0 + 63 > q0w);
      const int dq = myq - k0;
#pragma unroll
      for (int kb = 0; kb < 2; ++kb)
#pragma unroll
        for (int r = 0; r < 16; ++r) {
          float v = sacc[kb][r] * c1;
          if (needmask) {
            const int kk = kb * 32 + (r & 3) + 8 * (r >> 2) + 4 * hi;
            v = (kk <= dq) ? v : -3.0e38f;
          }
          sacc[kb][r] = v;
        }
      float mx = sacc[0][0];
#pragma unroll
      for (int kb = 0; kb < 2; ++kb)
#pragma unroll
        for (int r = 0; r < 16; ++r) mx = fmaxf(mx, sacc[kb][r]);
      mx = fmaxf(mx, __shfl_xor(mx, 32));
      if (!__all(mx <= mh + 11.5f)) {  // defer-max (T13)
        const float mnew = fmaxf(mh, mx);
        const float corr = exp2f(mh - mnew);
        mh = mnew;
        l *= corr;
#pragma unroll
        for (int r = 0; r < 16; ++r) {
          const float cr = __shfl(corr, (r & 3) + 8 * (r >> 2) + 4 * hi);
#pragma unroll
          for (int nf = 0; nf < 4; ++nf) oacc[nf][r] *= cr;
        }
      }
      float rs = 0.f;
#pragma unroll
      for (int kb = 0; kb < 2; ++kb)
#pragma unroll
        for (int r = 0; r < 16; ++r) {
          const float p = exp2f(sacc[kb][r] - mh);
          sacc[kb][r] = p;
          rs += p;
        }
      rs += __shfl_xor(rs, 32);
      l += rs;

      // --- P -> bf16 A-fragments (cvt_pk + half-swap) ---
      bf16x8 pa[4];
#pragma unroll
      for (int kb = 0; kb < 2; ++kb)
#pragma unroll
        for (int s = 0; s < 2; ++s) {
          const int b = s * 8;
          unsigned pk0 = cvtpk_bf16(sacc[kb][b + 0], sacc[kb][b + 1]);
          unsigned pk1 = cvtpk_bf16(sacc[kb][b + 2], sacc[kb][b + 3]);
          unsigned pk2 = cvtpk_bf16(sacc[kb][b + 4], sacc[kb][b + 5]);
          unsigned pk3 = cvtpk_bf16(sacc[kb][b + 6], sacc[kb][b + 7]);
          const unsigned sw0 = (unsigned)__shfl_xor((int)pk0, 32);
          const unsigned sw1 = (unsigned)__shfl_xor((int)pk1, 32);
          const unsigned sw2 = (unsigned)__shfl_xor((int)pk2, 32);
          const unsigned sw3 = (unsigned)__shfl_xor((int)pk3, 32);
          union { unsigned u[4]; bf16x8 v; } f;
          if (hi) { f.u[0] = sw2; f.u[1] = sw3; f.u[2] = pk2; f.u[3] = pk3; }
          else    { f.u[0] = pk0; f.u[1] = pk1; f.u[2] = sw0; f.u[3] = sw1; }
          pa[kb * 2 + s] = f.v;
        }

      // --- PV: oacc[nf] += P(32q x 16k) * V(16k x 32hd) ---
#pragma unroll
      for (int nf = 0; nf < 4; ++nf) {
        const int hd = 32 * nf + qc;
#pragma unroll
        for (int ks = 0; ks < 4; ++ks) {
          bf16x8 vf = *(const bf16x8*)((const char*)Vt[cur] + hd * 128 +
                                       (((2 * ks + hi) ^ (qc & 7)) << 4));
          oacc[nf] = __builtin_amdgcn_mfma_f32_32x32x16_bf16(pa[ks], vf, oacc[nf], 0, 0, 0);
        }
      }
    }

    // ---- write prefetched V into the other buffer; single barrier ----
#pragma unroll
    for (int w = 0; w < 16; ++w) {
      const int hd = hb + w;
      const unsigned val = (unsigned)r0.s[w] | ((unsigned)r1.s[w] << 16);
      *(unsigned*)((char*)Vt[nxt] + hd * 128 + (((kp >> 2) ^ (hd & 7)) << 4) + ((kp & 3) << 2)) = val;
    }
    __syncthreads();
  }

  // --- epilogue: normalize by l, store bf16 ---
  const float linv = 1.0f / l;
#pragma unroll
  for (int r = 0; r < 16; ++r) {
    const float li = __shfl(linv, (r & 3) + 8 * (r >> 2) + 4 * hi);
    const int q = q0w + (r & 3) + 8 * (r >> 2) + 4 * hi;
#pragma unroll
    for (int nf = 0; nf < 4; ++nf)
      Ob[(size_t)q * D_DIM + h * HDIM + 32 * nf + qc] = f2bf(oacc[nf][r] * li);
  }
}

extern "C" void kernel_launch(void* const* d_in, const int* in_sizes, int n_in,
                              void* d_out, int out_size, void* d_ws, size_t ws_size,
                              hipStream_t stream) {
  const float* X  = (const float*)d_in[0];
  const float* Wq = (const float*)d_in[1];
  const float* bq = (const float*)d_in[2];
  const float* Wk = (const float*)d_in[3];
  const float* bk = (const float*)d_in[4];
  const float* Wv = (const float*)d_in[5];
  const float* bv = (const float*)d_in[6];
  const float* Wo = (const float*)d_in[7];
  const float* bo = (const float*)d_in[8];
  float* out = (float*)d_out;

  unsigned short* ws = (unsigned short*)d_ws;
  const size_t SD = (size_t)S_LEN * D_DIM;
  const size_t DD = (size_t)D_DIM * D_DIM;
  unsigned short* Xb  = ws;
  unsigned short* Wqb = Xb + SD;
  unsigned short* Wkb = Wqb + DD;
  unsigned short* Wvb = Wkb + DD;
  unsigned short* Wob = Wvb + DD;
  unsigned short* Qb  = Wob + DD;
  unsigned short* Kb  = Qb + SD;
  unsigned short* Vb  = Kb + SD;
  unsigned short* AOb = Vb + SD;

  cvt_bf16<<<(int)(SD / 8 / 256), 256, 0, stream>>>(X, Xb, (int)SD);
  cvt_bf16<<<(int)(DD / 8 / 256), 256, 0, stream>>>(Wq, Wqb, (int)DD);
  cvt_bf16<<<(int)(DD / 8 / 256), 256, 0, stream>>>(Wk, Wkb, (int)DD);
  cvt_bf16<<<(int)(DD / 8 / 256), 256, 0, stream>>>(Wv, Wvb, (int)DD);
  cvt_bf16<<<(int)(DD / 8 / 256), 256, 0, stream>>>(Wo, Wob, (int)DD);

  dim3 gg(D_DIM / 128, S_LEN / 128);
  gemm_bt<true><<<gg, 256, 0, stream>>>(Xb, Wqb, bq, Qb, S_LEN, D_DIM, D_DIM);
  gemm_bt<true><<<gg, 256, 0, stream>>>(Xb, Wkb, bk, Kb, S_LEN, D_DIM, D_DIM);
  gemm_bt<true><<<gg, 256, 0, stream>>>(Xb, Wvb, bv, Vb, S_LEN, D_DIM, D_DIM);

  attn_fwd3<<<dim3(512), 256, 0, stream>>>(Qb, Kb, Vb, AOb);

  gemm_bt<false><<<gg, 256, 0, stream>>>(AOb, Wob, bo, out, S_LEN, D_DIM, D_DIM);
}

// Round 4
// 405.287 us; speedup vs baseline: 1.2413x; 1.2413x over previous
//
#include <hip/hip_runtime.h>
#include <stdint.h>

#define S_LEN 4096
#define D_DIM 2048
#define NHEAD 16
#define HDIM  128

typedef short bf16x8 __attribute__((ext_vector_type(8)));
typedef float f32x4  __attribute__((ext_vector_type(4)));
typedef float f32x16 __attribute__((ext_vector_type(16)));

__device__ __forceinline__ unsigned short f2bf(float x) {
  union { float f; unsigned u; } v; v.f = x;
  unsigned r = v.u + 0x7FFFu + ((v.u >> 16) & 1u);  // RNE
  return (unsigned short)(r >> 16);
}

__device__ __forceinline__ unsigned cvtpk_bf16(float lo, float hi_) {
  unsigned r;
  asm("v_cvt_pk_bf16_f32 %0, %1, %2" : "=v"(r) : "v"(lo), "v"(hi_));
  return r;
}

__device__ __forceinline__ void gload_lds16(const void* g, void* l) {
  __builtin_amdgcn_global_load_lds(
      (const __attribute__((address_space(1))) unsigned int*)g,
      (__attribute__((address_space(3))) unsigned int*)l, 16, 0, 0);
}

// ---------------- fused fp32 -> bf16 convert (X + 4 weights, one launch) ---
// Outputs are contiguous in ws: [Xb(2DD) | Wqb | Wkb | Wvb | Wob].
__global__ __launch_bounds__(256) void cvt_all(
    const float* __restrict__ X, const float* __restrict__ Wq,
    const float* __restrict__ Wk, const float* __restrict__ Wv,
    const float* __restrict__ Wo, unsigned short* __restrict__ out) {
  const size_t DD = (size_t)D_DIM * D_DIM;
  size_t i = ((size_t)blockIdx.x * 256 + threadIdx.x) * 8;
  const float* src; size_t off;
  if (i < 2 * DD)      { src = X;  off = i; }
  else if (i < 3 * DD) { src = Wq; off = i - 2 * DD; }
  else if (i < 4 * DD) { src = Wk; off = i - 3 * DD; }
  else if (i < 5 * DD) { src = Wv; off = i - 4 * DD; }
  else                 { src = Wo; off = i - 5 * DD; }
  float4 a = *(const float4*)(src + off);
  float4 b = *(const float4*)(src + off + 4);
  union { unsigned short s[8]; bf16x8 v; } o;
  o.s[0] = f2bf(a.x); o.s[1] = f2bf(a.y); o.s[2] = f2bf(a.z); o.s[3] = f2bf(a.w);
  o.s[4] = f2bf(b.x); o.s[5] = f2bf(b.y); o.s[6] = f2bf(b.z); o.s[7] = f2bf(b.w);
  *(bf16x8*)(out + i) = o.v;
}

// ---------------- bf16 GEMM, C[m,n] = sum_k A[m,k]*B[n,k] + bias[n] --------
template<bool OUT_BF16>
__global__ __launch_bounds__(256, 2) void gemm_bt(
    const unsigned short* __restrict__ A, const unsigned short* __restrict__ B,
    const float* __restrict__ bias, void* __restrict__ Cout,
    int M, int N, int K) {
  __shared__ __attribute__((aligned(16))) unsigned short As[128 * 32];
  __shared__ __attribute__((aligned(16))) unsigned short Bs[128 * 32];
  const int m0 = blockIdx.y * 128, n0 = blockIdx.x * 128;
  const int tid = threadIdx.x, lane = tid & 63, wv = tid >> 6;
  const int wm = wv >> 1, wn = wv & 1;
  const int rA = lane & 15, kb = (lane >> 4) * 8;

  f32x4 acc[4][4];
#pragma unroll
  for (int i = 0; i < 4; ++i)
#pragma unroll
    for (int j = 0; j < 4; ++j)
#pragma unroll
      for (int r = 0; r < 4; ++r) acc[i][j][r] = 0.f;

  for (int k0 = 0; k0 < K; k0 += 32) {
    __syncthreads();
#pragma unroll
    for (int p = 0; p < 2; ++p) {
      const int rr = (wv * 2 + p) * 16 + (lane >> 2);
      const int cc = lane & 3;
      gload_lds16(A + (size_t)(m0 + rr) * K + k0 + cc * 8, As + (wv * 2 + p) * 512);
      gload_lds16(B + (size_t)(n0 + rr) * K + k0 + cc * 8, Bs + (wv * 2 + p) * 512);
    }
    __syncthreads();
    bf16x8 af[4], bfr[4];
#pragma unroll
    for (int i = 0; i < 4; ++i)
      af[i] = *(const bf16x8*)(As + (wm * 64 + i * 16 + rA) * 32 + kb);
#pragma unroll
    for (int j = 0; j < 4; ++j)
      bfr[j] = *(const bf16x8*)(Bs + (wn * 64 + j * 16 + rA) * 32 + kb);
#pragma unroll
    for (int i = 0; i < 4; ++i)
#pragma unroll
      for (int j = 0; j < 4; ++j)
        acc[i][j] = __builtin_amdgcn_mfma_f32_16x16x32_bf16(af[i], bfr[j], acc[i][j], 0, 0, 0);
  }

  const int cR = (lane >> 4) * 4, cC = lane & 15;
#pragma unroll
  for (int j = 0; j < 4; ++j) {
    const int col = n0 + wn * 64 + j * 16 + cC;
    const float bv = bias[col];
#pragma unroll
    for (int i = 0; i < 4; ++i) {
      const int row0 = m0 + wm * 64 + i * 16 + cR;
#pragma unroll
      for (int r = 0; r < 4; ++r) {
        const float v = acc[i][j][r] + bv;
        if (OUT_BF16)
          ((unsigned short*)Cout)[(size_t)(row0 + r) * N + col] = f2bf(v);
        else
          ((float*)Cout)[(size_t)(row0 + r) * N + col] = v;
      }
    }
  }
}

// ---------------- attention helpers ----------------------------------------
__device__ __forceinline__ void stage_k(const unsigned short* __restrict__ Kb,
                                        unsigned short* ks, int k0, int h,
                                        int wv, int lane) {
#pragma unroll
  for (int p = 0; p < 4; ++p) {
    const int ob = wv * 4096 + p * 1024;   // wave-uniform LDS byte base
    const int o = ob + lane * 16;          // linear dest byte offset
    const int r = o >> 8, c = (o >> 4) & 15;
    gload_lds16(Kb + (size_t)(k0 + r) * D_DIM + h * HDIM + (c ^ (r & 7)) * 8,
                ks + ob / 2);
  }
}

struct vregs { uint4 u[4]; };

__device__ __forceinline__ vregs load_v(const unsigned short* __restrict__ Vb,
                                        int k0, int h, int kp, int hb) {
  vregs R;
  const unsigned short* s0 = Vb + (size_t)(k0 + 2 * kp) * D_DIM + h * HDIM + hb;
  R.u[0] = *(const uint4*)s0;           R.u[1] = *(const uint4*)(s0 + 8);
  R.u[2] = *(const uint4*)(s0 + D_DIM); R.u[3] = *(const uint4*)(s0 + D_DIM + 8);
  return R;
}

__device__ __forceinline__ void write_v(unsigned short* vt, const vregs& R,
                                        int kp, int hb) {
  union { uint4 u[4]; unsigned short s[32]; } t;
  t.u[0] = R.u[0]; t.u[1] = R.u[1]; t.u[2] = R.u[2]; t.u[3] = R.u[3];
#pragma unroll
  for (int w = 0; w < 16; ++w) {
    const int hd = hb + w;
    const unsigned val = (unsigned)t.s[w] | ((unsigned)t.s[16 + w] << 16);
    *(unsigned*)((char*)vt + hd * 128 + (((kp >> 2) ^ (hd & 7)) << 4) + ((kp & 3) << 2)) = val;
  }
}

// ---------------- causal flash attention, round 4 --------------------------
// r2 compute core (proven) + K/V double-buffer + ONE barrier per tile +
// async prefetch (T14) + setprio around MFMA clusters (T5) + LPT grid.
__global__ __launch_bounds__(256, 2) void attn_fwd4(
    const unsigned short* __restrict__ Qb, const unsigned short* __restrict__ Kb,
    const unsigned short* __restrict__ Vb, unsigned short* __restrict__ Ob) {
  __shared__ __attribute__((aligned(16))) unsigned short Ks[2][64 * 128];
  __shared__ __attribute__((aligned(16))) unsigned short Vt[2][128 * 64];
  const int bid = blockIdx.x;
  const int h = bid & 15;
  const int qi = 31 - (bid >> 4);     // LPT: heaviest q-tiles first
  const int q0 = qi * 128;
  const int tid = threadIdx.x, lane = tid & 63, wv = tid >> 6;
  const int qc = lane & 31, hi = lane >> 5;
  const int q0w = q0 + wv * 32;
  const int myq = q0w + qc;
  const int kp = tid & 31, hb = (tid >> 5) * 16;

  // Q as B-operand fragments: qf[sl] = Q[myq][sl*16 + hi*8 .. +8]
  bf16x8 qf[8];
#pragma unroll
  for (int sl = 0; sl < 8; ++sl)
    qf[sl] = *(const bf16x8*)(Qb + (size_t)myq * D_DIM + h * HDIM + sl * 16 + hi * 8);

  f32x16 oacc[4];
#pragma unroll
  for (int nf = 0; nf < 4; ++nf)
#pragma unroll
    for (int r = 0; r < 16; ++r) oacc[nf][r] = 0.f;
  float mh = -3.0e38f, l = 0.f;
  const float c1 = 0.08838834764831845f * 1.44269504089f;  // scale * log2(e)

  const int nt = q0 / 64 + 2;
  const int wqmax = q0w + 31;

  // ---- prologue: stage tile 0 into buffer 0 ----
  stage_k(Kb, &Ks[0][0], 0, h, wv, lane);
  {
    vregs R = load_v(Vb, 0, h, kp, hb);
    write_v(&Vt[0][0], R, kp, hb);
  }
  __syncthreads();

  for (int kt = 0; kt < nt; ++kt) {
    const int k0 = kt * 64;
    const int cur = kt & 1, nxt = cur ^ 1;
    const bool pre = (kt + 1 < nt);
    // ---- issue next tile's staging early (hidden under compute) ----
    if (pre) stage_k(Kb, &Ks[nxt][0], k0 + 64, h, wv, lane);
    vregs R;
    if (pre) R = load_v(Vb, k0 + 64, h, kp, hb);

    if (k0 <= wqmax) {
      // --- QK^T (swapped): sacc[kb] = S^T[32 keys][32 q] ---
      f32x16 sacc[2];
#pragma unroll
      for (int kb = 0; kb < 2; ++kb)
#pragma unroll
        for (int r = 0; r < 16; ++r) sacc[kb][r] = 0.f;
      __builtin_amdgcn_s_setprio(1);
#pragma unroll
      for (int sl = 0; sl < 8; ++sl) {
#pragma unroll
        for (int kb = 0; kb < 2; ++kb) {
          const int row = kb * 32 + qc;
          bf16x8 kfr = *(const bf16x8*)((const char*)&Ks[cur][0] + row * 256 +
                                        (((2 * sl + hi) ^ (qc & 7)) << 4));
          sacc[kb] = __builtin_amdgcn_mfma_f32_32x32x16_bf16(kfr, qf[sl], sacc[kb], 0, 0, 0);
        }
      }
      __builtin_amdgcn_s_setprio(0);

      // --- in-register online softmax (log2 domain) ---
      const bool needmask = (k0 + 63 > q0w);
      const int dq = myq - k0;
#pragma unroll
      for (int kb = 0; kb < 2; ++kb)
#pragma unroll
        for (int r = 0; r < 16; ++r) {
          float v = sacc[kb][r] * c1;
          if (needmask) {
            const int kk = kb * 32 + (r & 3) + 8 * (r >> 2) + 4 * hi;
            v = (kk <= dq) ? v : -3.0e38f;
          }
          sacc[kb][r] = v;
        }
      float mx = sacc[0][0];
#pragma unroll
      for (int kb = 0; kb < 2; ++kb)
#pragma unroll
        for (int r = 0; r < 16; ++r) mx = fmaxf(mx, sacc[kb][r]);
      mx = fmaxf(mx, __shfl_xor(mx, 32));
      if (!__all(mx <= mh + 11.5f)) {  // defer-max (T13)
        const float mnew = fmaxf(mh, mx);
        const float corr = exp2f(mh - mnew);
        mh = mnew;
        l *= corr;
#pragma unroll
        for (int r = 0; r < 16; ++r) {
          const float cr = __shfl(corr, (r & 3) + 8 * (r >> 2) + 4 * hi);
#pragma unroll
          for (int nf = 0; nf < 4; ++nf) oacc[nf][r] *= cr;
        }
      }
      float rs = 0.f;
#pragma unroll
      for (int kb = 0; kb < 2; ++kb)
#pragma unroll
        for (int r = 0; r < 16; ++r) {
          const float p = exp2f(sacc[kb][r] - mh);
          sacc[kb][r] = p;
          rs += p;
        }
      rs += __shfl_xor(rs, 32);
      l += rs;

      // --- P -> bf16 A-fragments (cvt_pk + half-swap) ---
      bf16x8 pa[4];
#pragma unroll
      for (int kb = 0; kb < 2; ++kb)
#pragma unroll
        for (int s = 0; s < 2; ++s) {
          const int b = s * 8;
          unsigned pk0 = cvtpk_bf16(sacc[kb][b + 0], sacc[kb][b + 1]);
          unsigned pk1 = cvtpk_bf16(sacc[kb][b + 2], sacc[kb][b + 3]);
          unsigned pk2 = cvtpk_bf16(sacc[kb][b + 4], sacc[kb][b + 5]);
          unsigned pk3 = cvtpk_bf16(sacc[kb][b + 6], sacc[kb][b + 7]);
          const unsigned sw0 = (unsigned)__shfl_xor((int)pk0, 32);
          const unsigned sw1 = (unsigned)__shfl_xor((int)pk1, 32);
          const unsigned sw2 = (unsigned)__shfl_xor((int)pk2, 32);
          const unsigned sw3 = (unsigned)__shfl_xor((int)pk3, 32);
          union { unsigned u[4]; bf16x8 v; } f;
          if (hi) { f.u[0] = sw2; f.u[1] = sw3; f.u[2] = pk2; f.u[3] = pk3; }
          else    { f.u[0] = pk0; f.u[1] = pk1; f.u[2] = sw0; f.u[3] = sw1; }
          pa[kb * 2 + s] = f.v;
        }

      // --- PV: oacc[nf] += P(32q x 16k) * V(16k x 32hd) ---
      __builtin_amdgcn_s_setprio(1);
#pragma unroll
      for (int nf = 0; nf < 4; ++nf) {
        const int hd = 32 * nf + qc;
#pragma unroll
        for (int ks = 0; ks < 4; ++ks) {
          bf16x8 vf = *(const bf16x8*)((const char*)&Vt[cur][0] + hd * 128 +
                                       (((2 * ks + hi) ^ (qc & 7)) << 4));
          oacc[nf] = __builtin_amdgcn_mfma_f32_32x32x16_bf16(pa[ks], vf, oacc[nf], 0, 0, 0);
        }
      }
      __builtin_amdgcn_s_setprio(0);
    }

    if (pre) {
      write_v(&Vt[nxt][0], R, kp, hb);
      __syncthreads();  // K[nxt] landed (vmcnt drain) + V[nxt] visible + cur reads done
    }
  }

  // --- epilogue: normalize by l, store bf16 ---
  const float linv = 1.0f / l;
#pragma unroll
  for (int r = 0; r < 16; ++r) {
    const float li = __shfl(linv, (r & 3) + 8 * (r >> 2) + 4 * hi);
    const int q = q0w + (r & 3) + 8 * (r >> 2) + 4 * hi;
#pragma unroll
    for (int nf = 0; nf < 4; ++nf)
      Ob[(size_t)q * D_DIM + h * HDIM + 32 * nf + qc] = f2bf(oacc[nf][r] * li);
  }
}

extern "C" void kernel_launch(void* const* d_in, const int* in_sizes, int n_in,
                              void* d_out, int out_size, void* d_ws, size_t ws_size,
                              hipStream_t stream) {
  const float* X  = (const float*)d_in[0];
  const float* Wq = (const float*)d_in[1];
  const float* bq = (const float*)d_in[2];
  const float* Wk = (const float*)d_in[3];
  const float* bk = (const float*)d_in[4];
  const float* Wv = (const float*)d_in[5];
  const float* bv = (const float*)d_in[6];
  const float* Wo = (const float*)d_in[7];
  const float* bo = (const float*)d_in[8];
  float* out = (float*)d_out;

  unsigned short* ws = (unsigned short*)d_ws;
  const size_t SD = (size_t)S_LEN * D_DIM;
  const size_t DD = (size_t)D_DIM * D_DIM;
  unsigned short* Xb  = ws;
  unsigned short* Wqb = Xb + SD;
  unsigned short* Wkb = Wqb + DD;
  unsigned short* Wvb = Wkb + DD;
  unsigned short* Wob = Wvb + DD;
  unsigned short* Qb  = Wob + DD;
  unsigned short* Kb  = Qb + SD;
  unsigned short* Vb  = Kb + SD;
  unsigned short* AOb = Vb + SD;

  // one fused convert: [Xb | Wqb | Wkb | Wvb | Wob] = 6*DD elements
  cvt_all<<<(int)(6 * DD / 8 / 256), 256, 0, stream>>>(X, Wq, Wk, Wv, Wo, Xb);

  dim3 gg(D_DIM / 128, S_LEN / 128);
  gemm_bt<true><<<gg, 256, 0, stream>>>(Xb, Wqb, bq, Qb, S_LEN, D_DIM, D_DIM);
  gemm_bt<true><<<gg, 256, 0, stream>>>(Xb, Wkb, bk, Kb, S_LEN, D_DIM, D_DIM);
  gemm_bt<true><<<gg, 256, 0, stream>>>(Xb, Wvb, bv, Vb, S_LEN, D_DIM, D_DIM);

  attn_fwd4<<<dim3(512), 256, 0, stream>>>(Qb, Kb, Vb, AOb);

  gemm_bt<false><<<gg, 256, 0, stream>>>(AOb, Wob, bo, out, S_LEN, D_DIM, D_DIM);
}